// Round 14
// baseline (3974.009 us; speedup 1.0000x reference)
//
#include <hip/hip_runtime.h>
#include <math.h>

#define LN2F 0.69314718055994530942f
#define PI_F 3.14159265358979323846f
constexpr float DMU = 4.0f/49.0f;          // gaussian spacing, linspace(0,4,50)
constexpr float GC  = -0.5f/(DMU*DMU);     // smearing coeff

typedef __bf16 bf16x8 __attribute__((ext_vector_type(8)));
typedef __bf16 bf16x2 __attribute__((ext_vector_type(2)));
typedef float  f32x4  __attribute__((ext_vector_type(4)));

// fast-math: v_exp_f32 / v_log_f32 / v_rcp_f32
__device__ __forceinline__ float sspf(float x){
  return fmaxf(x, 0.f) + __logf(1.f + __expf(-fabsf(x))) - LN2F;
}
__device__ __forceinline__ float sigf(float x){
  return __builtin_amdgcn_rcpf(1.f + __expf(-x));
}

// ---------------------------------------------------------------------------
// bf16 MFMA node GEMM: out[M,NT*16] = epi( A'[M,KK] @ B ), fp32 in/out.
// ---------------------------------------------------------------------------
template<int KK,int NT,int ATR,bool BIAS,int OTR,bool RES>
__global__ __launch_bounds__(256) void ngemm_k(
    const float* __restrict__ A, const float* __restrict__ aux,
    const float* __restrict__ auxvec, const __bf16* __restrict__ Bt,
    const float* __restrict__ bias, const float* __restrict__ res,
    float* __restrict__ out, int M)
{
  constexpr int NN = NT*16;
  constexpr int KP = KK + 8;
  __shared__ __align__(16) __bf16 As[64][KP];
  const int t = threadIdx.x;
  const int m0 = blockIdx.x*64;

  #pragma unroll
  for (int it=0; it<(64*KK)/(8*256); ++it){
    int p = t + it*256;
    int row = p / (KK/8);
    int ko = (p % (KK/8))*8;
    float v[8];
    if (m0+row < M){
      float4 v0 = *(const float4*)(A + (size_t)(m0+row)*KK + ko);
      float4 v1 = *(const float4*)(A + (size_t)(m0+row)*KK + ko + 4);
      v[0]=v0.x; v[1]=v0.y; v[2]=v0.z; v[3]=v0.w;
      v[4]=v1.x; v[5]=v1.y; v[6]=v1.z; v[7]=v1.w;
      if constexpr (ATR==1){
        #pragma unroll
        for (int j=0;j<8;j++) v[j] = sspf(v[j]);
      } else if constexpr (ATR==2){
        float4 a0 = *(const float4*)(aux + (size_t)(m0+row)*KK + ko);
        float4 a1 = *(const float4*)(aux + (size_t)(m0+row)*KK + ko + 4);
        v[0]*=sigf(a0.x); v[1]*=sigf(a0.y); v[2]*=sigf(a0.z); v[3]*=sigf(a0.w);
        v[4]*=sigf(a1.x); v[5]*=sigf(a1.y); v[6]*=sigf(a1.z); v[7]*=sigf(a1.w);
      } else if constexpr (ATR==3){
        #pragma unroll
        for (int j=0;j<8;j++) v[j] = auxvec[ko+j]*sigf(v[j]);
      }
    } else {
      #pragma unroll
      for (int j=0;j<8;j++) v[j] = 0.f;
    }
    bf16x8 o;
    #pragma unroll
    for (int j=0;j<8;j++) o[j] = (__bf16)v[j];
    *(bf16x8*)&As[row][ko] = o;
  }
  __syncthreads();

  const int wid = t>>6, lane = t&63, quad = lane>>4, ln = lane&15;
  f32x4 acc[NT];
  #pragma unroll
  for (int nt=0;nt<NT;nt++) acc[nt] = (f32x4){0.f,0.f,0.f,0.f};

  #pragma unroll
  for (int ks=0; ks<KK; ks+=32){
    bf16x8 a = *(const bf16x8*)&As[wid*16 + ln][ks + quad*8];
    #pragma unroll
    for (int nt=0; nt<NT; nt++){
      bf16x8 b = *(const bf16x8*)(Bt + (size_t)(nt*16+ln)*KK + ks + quad*8);
      acc[nt] = __builtin_amdgcn_mfma_f32_16x16x32_bf16(a, b, acc[nt], 0, 0, 0);
    }
  }

  #pragma unroll
  for (int reg=0; reg<4; reg++){
    int r = m0 + wid*16 + quad*4 + reg;
    if (r < M){
      #pragma unroll
      for (int nt=0; nt<NT; nt++){
        int c = nt*16 + ln;
        float v = acc[nt][reg];
        if constexpr (BIAS) v += bias[c];
        if constexpr (OTR==1) v = sspf(v);
        if constexpr (RES) v += res[(size_t)r*NN + c];
        out[(size_t)r*NN + c] = v;
      }
    }
  }
}

// ---------------------------------------------------------------------------
// Fused FORWARD edge kernel (W2 from global, 18KB LDS, natural occupancy)
// ---------------------------------------------------------------------------
__global__ __launch_bounds__(256) void fwd_edge_k(
    const float* __restrict__ wv, const float* __restrict__ Cv,
    const int* __restrict__ ei, int E,
    const __bf16* __restrict__ W1t, const float* __restrict__ b1,
    const __bf16* __restrict__ W2t, const float* __restrict__ b2,
    const float* __restrict__ xh, float* __restrict__ agg)
{
  __shared__ __align__(16) __bf16 s1t[64][136];    // 17.4 KB
  __shared__ float wrow[64], Ce[64];
  __shared__ int rowi[64], coli[64];
  const int t = threadIdx.x;
  const int e0 = blockIdx.x*64;

  if (t < 64){
    int e = e0 + t;
    bool ok = e < E;
    wrow[t] = ok ? wv[e] : 0.f;
    Ce[t]   = ok ? Cv[e] : 0.f;
    rowi[t] = ok ? ei[e] : 0;
    coli[t] = ok ? ei[E+e] : 0;
  }
  __syncthreads();

  const int wid = t>>6, lane = t&63, quad = lane>>4, ln = lane&15;
  f32x4 acc[8];
  #pragma unroll
  for (int nt=0;nt<8;nt++) acc[nt] = (f32x4){0.f,0.f,0.f,0.f};

  // ---- GEMM1: t1 = ea @ W1 ----
  const float wa = wrow[wid*16 + ln];
  #pragma unroll
  for (int ks=0; ks<64; ks+=32){
    bf16x8 a;
    #pragma unroll
    for (int j=0;j<8;j++){
      int k = ks + quad*8 + j;
      float d = wa - (float)k*DMU;
      a[j] = (k<50) ? (__bf16)__expf(GC*d*d) : (__bf16)0.f;
    }
    #pragma unroll
    for (int nt=0; nt<8; nt++){
      bf16x8 b = *(const bf16x8*)(W1t + (size_t)(nt*16+ln)*64 + ks + quad*8);
      acc[nt] = __builtin_amdgcn_mfma_f32_16x16x32_bf16(a, b, acc[nt], 0, 0, 0);
    }
  }
  #pragma unroll
  for (int nt=0; nt<8; nt++){
    int c = nt*16 + ln;
    float bb = b1[c];
    #pragma unroll
    for (int reg=0; reg<4; reg++){
      int r = wid*16 + quad*4 + reg;
      s1t[r][c] = (__bf16)sspf(acc[nt][reg] + bb);
    }
  }
  __syncthreads();

  // ---- GEMM2: Wf = s1 @ W2 (B from global) ----
  #pragma unroll
  for (int nt=0;nt<8;nt++) acc[nt] = (f32x4){0.f,0.f,0.f,0.f};
  #pragma unroll
  for (int ks=0; ks<128; ks+=32){
    bf16x8 a = *(const bf16x8*)&s1t[wid*16 + ln][ks + quad*8];
    #pragma unroll
    for (int nt=0; nt<8; nt++){
      bf16x8 b = *(const bf16x8*)(W2t + (size_t)(nt*16+ln)*128 + ks + quad*8);
      acc[nt] = __builtin_amdgcn_mfma_f32_16x16x32_bf16(a, b, acc[nt], 0, 0, 0);
    }
  }

  // ---- scatter: agg[col] += xh[row]*(Wf+b2)*C ----
  #pragma unroll
  for (int reg=0; reg<4; reg++){
    int r = wid*16 + quad*4 + reg;
    int e = e0 + r;
    if (e < E){
      float ce = Ce[r];
      size_t ri = (size_t)rowi[r]*128;
      size_t ci = (size_t)coli[r]*128;
      #pragma unroll
      for (int nt=0; nt<8; nt++){
        int c = nt*16 + ln;
        float wf = acc[nt][reg] + b2[c];
        atomicAdd(&agg[ci + c], xh[ri + c]*ce*wf);
      }
    }
  }
}

// ---------------------------------------------------------------------------
// Fused BACKWARD edge kernel: 128 edges/block, 2 m-tiles per wave (2x ILP).
// sig stored packed bf16x2 to stay inside the 128-unified-reg envelope.
// ---------------------------------------------------------------------------
__global__ __launch_bounds__(256,4) void bwd_edge_k(
    const float* __restrict__ wv, const float* __restrict__ Cv,
    const int* __restrict__ ei, int E,
    const __bf16* __restrict__ W1t, const float* __restrict__ b1,
    const __bf16* __restrict__ W2t, const float* __restrict__ b2,
    const __bf16* __restrict__ W2c, const __bf16* __restrict__ W1c,
    const float* __restrict__ dagg, const float* __restrict__ xh,
    float* __restrict__ dxh, float* __restrict__ dC, float* __restrict__ dw,
    int accum)
{
  __shared__ __align__(16) __bf16 tb[128][136];    // 34.8 KB
  __shared__ float wrow[128], Ce[128];
  __shared__ int rowi[128], coli[128];
  const int t = threadIdx.x;
  const int e0 = blockIdx.x*128;

  if (t < 128){
    int e = e0 + t;
    bool ok = e < E;
    wrow[t] = ok ? wv[e] : 0.f;
    Ce[t]   = ok ? Cv[e] : 0.f;
    rowi[t] = ok ? ei[e] : 0;
    coli[t] = ok ? ei[E+e] : 0;
  }
  __syncthreads();

  const int wid = t>>6, lane = t&63, quad = lane>>4, ln = lane&15;
  const int mb = wid*32;
  f32x4 acc[2][8];
  bf16x2 sigp[2][8][2];
  #pragma unroll
  for (int mt=0;mt<2;mt++)
    #pragma unroll
    for (int nt=0;nt<8;nt++) acc[mt][nt] = (f32x4){0.f,0.f,0.f,0.f};

  // ---- GEMM1: t1 = ea @ W1 ; keep sig(t1) packed, store ssp(t1) ----
  const float wa0 = wrow[mb + ln];
  const float wa1 = wrow[mb + 16 + ln];
  #pragma unroll
  for (int ks=0; ks<64; ks+=32){
    bf16x8 a0, a1;
    #pragma unroll
    for (int j=0;j<8;j++){
      int k = ks + quad*8 + j;
      float d0 = wa0 - (float)k*DMU;
      float d1 = wa1 - (float)k*DMU;
      a0[j] = (k<50) ? (__bf16)__expf(GC*d0*d0) : (__bf16)0.f;
      a1[j] = (k<50) ? (__bf16)__expf(GC*d1*d1) : (__bf16)0.f;
    }
    #pragma unroll
    for (int nt=0; nt<8; nt++){
      bf16x8 b = *(const bf16x8*)(W1t + (size_t)(nt*16+ln)*64 + ks + quad*8);
      acc[0][nt] = __builtin_amdgcn_mfma_f32_16x16x32_bf16(a0, b, acc[0][nt], 0, 0, 0);
      acc[1][nt] = __builtin_amdgcn_mfma_f32_16x16x32_bf16(a1, b, acc[1][nt], 0, 0, 0);
    }
  }
  #pragma unroll
  for (int nt=0; nt<8; nt++){
    int c = nt*16 + ln;
    float bb = b1[c];
    #pragma unroll
    for (int mt=0; mt<2; mt++){
      #pragma unroll
      for (int reg=0; reg<4; reg++){
        int r = mb + mt*16 + quad*4 + reg;
        float t1 = acc[mt][nt][reg] + bb;
        sigp[mt][nt][reg>>1][reg&1] = (__bf16)sigf(t1);
        tb[r][c] = (__bf16)sspf(t1);
      }
    }
  }
  __syncthreads();

  // ---- GEMM2: Wf = s1 @ W2 (B from global, reused across m-tiles) ----
  #pragma unroll
  for (int mt=0;mt<2;mt++)
    #pragma unroll
    for (int nt=0;nt<8;nt++) acc[mt][nt] = (f32x4){0.f,0.f,0.f,0.f};
  #pragma unroll
  for (int ks=0; ks<128; ks+=32){
    bf16x8 a0 = *(const bf16x8*)&tb[mb + ln][ks + quad*8];
    bf16x8 a1 = *(const bf16x8*)&tb[mb + 16 + ln][ks + quad*8];
    #pragma unroll
    for (int nt=0; nt<8; nt++){
      bf16x8 b = *(const bf16x8*)(W2t + (size_t)(nt*16+ln)*128 + ks + quad*8);
      acc[0][nt] = __builtin_amdgcn_mfma_f32_16x16x32_bf16(a0, b, acc[0][nt], 0, 0, 0);
      acc[1][nt] = __builtin_amdgcn_mfma_f32_16x16x32_bf16(a1, b, acc[1][nt], 0, 0, 0);
    }
  }
  __syncthreads();   // reads of tb (s1) done

  // ---- edge step: dC, dxh scatter, dWf -> tb ----
  #pragma unroll
  for (int mt=0; mt<2; mt++){
    #pragma unroll
    for (int reg=0; reg<4; reg++){
      int r = mb + mt*16 + quad*4 + reg;
      int e = e0 + r;
      float dcp = 0.f;
      if (e < E){
        float ce = Ce[r];
        size_t ri = (size_t)rowi[r]*128;
        size_t ci = (size_t)coli[r]*128;
        #pragma unroll
        for (int nt=0; nt<8; nt++){
          int c = nt*16 + ln;
          float wf = acc[mt][nt][reg] + b2[c];
          float da = dagg[ci + c];
          float xv = xh[ri + c];
          dcp += da*xv*wf;
          atomicAdd(&dxh[ri + c], da*ce*wf);
          tb[r][c] = (__bf16)(da*xv*ce);
        }
      } else {
        #pragma unroll
        for (int nt=0; nt<8; nt++) tb[r][nt*16+ln] = (__bf16)0.f;
      }
      dcp += __shfl_xor(dcp, 1);
      dcp += __shfl_xor(dcp, 2);
      dcp += __shfl_xor(dcp, 4);
      dcp += __shfl_xor(dcp, 8);
      if (ln==0 && e < E) dC[e] = accum ? (dC[e]+dcp) : dcp;
    }
  }
  __syncthreads();

  // ---- GEMM3: dt1 = (dWf @ W2^T) * sig (B from global W2c) ----
  #pragma unroll
  for (int mt=0;mt<2;mt++)
    #pragma unroll
    for (int nt=0;nt<8;nt++) acc[mt][nt] = (f32x4){0.f,0.f,0.f,0.f};
  #pragma unroll
  for (int ks=0; ks<128; ks+=32){
    bf16x8 a0 = *(const bf16x8*)&tb[mb + ln][ks + quad*8];
    bf16x8 a1 = *(const bf16x8*)&tb[mb + 16 + ln][ks + quad*8];
    #pragma unroll
    for (int nt=0; nt<8; nt++){
      bf16x8 b = *(const bf16x8*)(W2c + (size_t)(nt*16+ln)*128 + ks + quad*8);
      acc[0][nt] = __builtin_amdgcn_mfma_f32_16x16x32_bf16(a0, b, acc[0][nt], 0, 0, 0);
      acc[1][nt] = __builtin_amdgcn_mfma_f32_16x16x32_bf16(a1, b, acc[1][nt], 0, 0, 0);
    }
  }
  __syncthreads();   // reads of tb (dWf) done
  #pragma unroll
  for (int nt=0; nt<8; nt++){
    int c = nt*16 + ln;
    #pragma unroll
    for (int mt=0; mt<2; mt++){
      #pragma unroll
      for (int reg=0; reg<4; reg++){
        int r = mb + mt*16 + quad*4 + reg;
        tb[r][c] = (__bf16)(acc[mt][nt][reg] * (float)sigp[mt][nt][reg>>1][reg&1]);
      }
    }
  }
  __syncthreads();

  // ---- GEMM4: dea = dt1 @ W1^T ; contract to dw ----
  #pragma unroll
  for (int mt=0;mt<2;mt++)
    #pragma unroll
    for (int nt=0;nt<4;nt++) acc[mt][nt] = (f32x4){0.f,0.f,0.f,0.f};
  #pragma unroll
  for (int ks=0; ks<128; ks+=32){
    bf16x8 a0 = *(const bf16x8*)&tb[mb + ln][ks + quad*8];
    bf16x8 a1 = *(const bf16x8*)&tb[mb + 16 + ln][ks + quad*8];
    #pragma unroll
    for (int nt=0; nt<4; nt++){
      bf16x8 b = *(const bf16x8*)(W1c + (size_t)(nt*16+ln)*128 + ks + quad*8);
      acc[0][nt] = __builtin_amdgcn_mfma_f32_16x16x32_bf16(a0, b, acc[0][nt], 0, 0, 0);
      acc[1][nt] = __builtin_amdgcn_mfma_f32_16x16x32_bf16(a1, b, acc[1][nt], 0, 0, 0);
    }
  }
  #pragma unroll
  for (int mt=0; mt<2; mt++){
    #pragma unroll
    for (int reg=0; reg<4; reg++){
      int r = mb + mt*16 + quad*4 + reg;
      int e = e0 + r;
      float w = wrow[r];
      float s = 0.f;
      #pragma unroll
      for (int nt=0; nt<4; nt++){
        int c = nt*16 + ln;
        if (c < 50){
          float d = w - (float)c*DMU;
          s += acc[mt][nt][reg] * (2.f*GC*d) * __expf(GC*d*d);
        }
      }
      s += __shfl_xor(s, 1);
      s += __shfl_xor(s, 2);
      s += __shfl_xor(s, 4);
      s += __shfl_xor(s, 8);
      if (ln==0 && e < E) dw[e] = accum ? (dw[e]+s) : s;
    }
  }
}

// ---------------------------------------------------------------------------
// one-time bf16 weight conversions
// ---------------------------------------------------------------------------
__global__ void convw_k(const float* __restrict__ w1, const float* __restrict__ w2,
                        __bf16* __restrict__ W1t, __bf16* __restrict__ W2t,
                        __bf16* __restrict__ W2c, __bf16* __restrict__ W1c, int total)
{
  int idx = blockIdx.x*256 + threadIdx.x;
  if (idx >= total) return;
  int l = idx / 49152;
  int r = idx % 49152;
  if (r < 8192){                       // W1t[n][k] = w1[k][n], k<50
    int n = r / 64, k = r % 64;
    float v = (k<50) ? w1[(size_t)l*6400 + k*128 + n] : 0.f;
    W1t[(size_t)l*8192 + r] = (__bf16)v;
  } else if (r < 24576){               // W2t[n][k] = w2[k][n]
    int r2 = r - 8192;
    int n = r2 / 128, k = r2 % 128;
    W2t[(size_t)l*16384 + r2] = (__bf16)w2[(size_t)l*16384 + k*128 + n];
  } else if (r < 40960){               // W2c = w2 (elementwise)
    int r2 = r - 24576;
    W2c[(size_t)l*16384 + r2] = (__bf16)w2[(size_t)l*16384 + r2];
  } else {                             // W1c[n][k] = w1[n][k], n<50
    int r2 = r - 40960;
    int n = r2 / 128, k = r2 % 128;
    float v = (n<50) ? w1[(size_t)l*6400 + n*128 + k] : 0.f;
    W1c[(size_t)l*8192 + r2] = (__bf16)v;
  }
}

// node-weight bf16 layouts: F = B^T of non-transposed use, T = row-major cast
__global__ void convnw_k(const float* __restrict__ cw1, const float* __restrict__ cw2,
                         const float* __restrict__ lw,
                         __bf16* __restrict__ cw1F, __bf16* __restrict__ cw2F,
                         __bf16* __restrict__ lwF,
                         __bf16* __restrict__ cw1T, __bf16* __restrict__ cw2T,
                         __bf16* __restrict__ lwT, int total)
{
  int idx = blockIdx.x*256 + threadIdx.x;
  if (idx >= total) return;
  int l = idx / 16384;
  int r = idx % 16384;
  int a = r / 128, b = r % 128;
  size_t off = (size_t)l*16384;
  cw1F[off+r] = (__bf16)cw1[off + (size_t)b*128 + a];
  cw2F[off+r] = (__bf16)cw2[off + (size_t)b*128 + a];
  lwF [off+r] = (__bf16)lw [off + (size_t)b*128 + a];
  cw1T[off+r] = (__bf16)cw1[off + r];
  cw2T[off+r] = (__bf16)cw2[off + r];
  lwT [off+r] = (__bf16)lw [off + r];
}
__global__ void convhw_k(const float* __restrict__ o1,
                         __bf16* __restrict__ o1F, __bf16* __restrict__ o1T)
{
  int idx = blockIdx.x*256 + threadIdx.x;
  if (idx < 8192){
    int n = idx / 128, k = idx % 128;
    o1F[idx] = (__bf16)o1[(size_t)k*64 + n];
    o1T[idx] = (__bf16)o1[idx];
  }
}

// ---------------------------------------------------------------------------
__global__ void edge_geom_k(const float* __restrict__ pos, const int* __restrict__ ei,
                            const float* __restrict__ off, const float* __restrict__ cell,
                            float* __restrict__ wv, float* __restrict__ Cv, int E)
{
  int e = blockIdx.x*256 + threadIdx.x;
  if (e>=E) return;
  int r = ei[e], c = ei[E+e];
  float o0=off[3*e], o1=off[3*e+1], o2=off[3*e+2];
  float d0 = o0*cell[0] + o1*cell[3] + o2*cell[6];
  float d1 = o0*cell[1] + o1*cell[4] + o2*cell[7];
  float d2 = o0*cell[2] + o1*cell[5] + o2*cell[8];
  float v0 = pos[3*r+0]-pos[3*c+0]+d0;
  float v1 = pos[3*r+1]-pos[3*c+1]+d1;
  float v2 = pos[3*r+2]-pos[3*c+2]+d2;
  float w = sqrtf(v0*v0+v1*v1+v2*v2);
  wv[e]=w;
  Cv[e]=0.5f*cosf(w*(PI_F/4.0f)) + 0.5f;
}

__global__ void embed_k(const float* __restrict__ emb, const int* __restrict__ z,
                        float* __restrict__ h, int total){
  int i = blockIdx.x*256 + threadIdx.x;
  if (i < total){ int n=i>>7, j=i&127; h[i] = emb[(size_t)z[n]*128 + j]; }
}

// readout energy
__global__ void head_k(const float* __restrict__ u, const float* __restrict__ o2,
                       const float* __restrict__ o2b, float* __restrict__ out0, int N){
  int n = blockIdx.x*256 + threadIdx.x;
  float s = 0.f;
  if (n < N){
    #pragma unroll
    for (int k=0;k<64;k+=4){
      float4 uv = *(const float4*)(u + (size_t)n*64 + k);
      float4 ov = *(const float4*)(o2 + k);
      s += sspf(uv.x)*ov.x + sspf(uv.y)*ov.y + sspf(uv.z)*ov.z + sspf(uv.w)*ov.w;
    }
  }
  #pragma unroll
  for (int m=1;m<64;m<<=1) s += __shfl_xor(s, m);
  __shared__ float red[4];
  int lane = threadIdx.x&63, w = threadIdx.x>>6;
  if (lane==0) red[w]=s;
  __syncthreads();
  if (threadIdx.x==0){
    float tot = red[0]+red[1]+red[2]+red[3];
    if (blockIdx.x==0) tot += (float)N * o2b[0];
    atomicAdd(out0, tot);
  }
}

// forces: recompute vec, dvec = vec*(dw + dC*dCdw)/w, atomic scatter to f
__global__ void force_k(const float* __restrict__ dw, const float* __restrict__ dC,
                        const float* __restrict__ wv,
                        const float* __restrict__ pos, const int* __restrict__ ei,
                        const float* __restrict__ off, const float* __restrict__ cell,
                        float* __restrict__ f, int E)
{
  int e = blockIdx.x*256 + threadIdx.x;
  if (e>=E) return;
  int r = ei[e], c = ei[E+e];
  float o0=off[3*e], o1=off[3*e+1], o2=off[3*e+2];
  float d0 = o0*cell[0] + o1*cell[3] + o2*cell[6];
  float d1 = o0*cell[1] + o1*cell[4] + o2*cell[7];
  float d2 = o0*cell[2] + o1*cell[5] + o2*cell[8];
  float v0 = pos[3*r+0]-pos[3*c+0]+d0;
  float v1 = pos[3*r+1]-pos[3*c+1]+d1;
  float v2 = pos[3*r+2]-pos[3*c+2]+d2;
  float w = wv[e];
  float dwt = dw[e] + dC[e] * (-0.5f*(PI_F/4.0f)) * __sinf(w*(PI_F/4.0f));
  float s = dwt / w;
  atomicAdd(&f[3*r+0], -v0*s); atomicAdd(&f[3*r+1], -v1*s); atomicAdd(&f[3*r+2], -v2*s);
  atomicAdd(&f[3*c+0],  v0*s); atomicAdd(&f[3*c+1],  v1*s); atomicAdd(&f[3*c+2],  v2*s);
}

// ---------------------------------------------------------------------------
extern "C" void kernel_launch(void* const* d_in, const int* in_sizes, int n_in,
                              void* d_out, int out_size, void* d_ws, size_t ws_size,
                              hipStream_t stream)
{
  const int N = in_sizes[0];
  const int E = in_sizes[2]/2;
  const int L = 6;
  const int* z        = (const int*)d_in[0];
  const float* pos    = (const float*)d_in[1];
  const int* ei       = (const int*)d_in[2];
  const float* offset = (const float*)d_in[3];
  const float* cell   = (const float*)d_in[4];
  const float* emb    = (const float*)d_in[5];
  const float* mlp_w1 = (const float*)d_in[6];
  const float* mlp_b1 = (const float*)d_in[7];
  const float* mlp_w2 = (const float*)d_in[8];
  const float* mlp_b2 = (const float*)d_in[9];
  const float* conv_w1= (const float*)d_in[10];
  const float* conv_w2= (const float*)d_in[11];
  const float* conv_b2= (const float*)d_in[12];
  const float* lin_w  = (const float*)d_in[13];
  const float* lin_b  = (const float*)d_in[14];
  const float* out1_w = (const float*)d_in[15];
  const float* out1_b = (const float*)d_in[16];
  const float* out2_w = (const float*)d_in[17];
  const float* out2_b = (const float*)d_in[18];
  float* out = (float*)d_out;

  char* wp = (char*)d_ws;
  auto alloc = [&](size_t bytes)->char*{ char* p = wp; wp += (bytes + 255) & ~(size_t)255; return p; };
  float* wbuf = (float*)alloc((size_t)E*4);
  float* Cbuf = (float*)alloc((size_t)E*4);
  float* dCb  = (float*)alloc((size_t)E*4);
  float* dwb  = (float*)alloc((size_t)E*4);
  float* xh   = (float*)alloc((size_t)L*N*128*4);
  float* mbuf = (float*)alloc((size_t)L*N*128*4);
  float* ubuf = (float*)alloc((size_t)N*64*4);
  float* hbuf = (float*)alloc((size_t)N*128*4);
  float* Gbuf = (float*)alloc((size_t)N*128*4);
  float* bufA = (float*)alloc((size_t)N*128*4);
  float* bufB = (float*)alloc((size_t)N*128*4);
  float* bufC = (float*)alloc((size_t)N*128*4);   // dxh
  float* aggb = (float*)alloc((size_t)N*128*4);
  __bf16* W1t = (__bf16*)alloc((size_t)L*8192*2);
  __bf16* W2t = (__bf16*)alloc((size_t)L*16384*2);
  __bf16* W2c = (__bf16*)alloc((size_t)L*16384*2);
  __bf16* W1c = (__bf16*)alloc((size_t)L*8192*2);
  __bf16* cw1F = (__bf16*)alloc((size_t)L*16384*2);
  __bf16* cw2F = (__bf16*)alloc((size_t)L*16384*2);
  __bf16* lwF  = (__bf16*)alloc((size_t)L*16384*2);
  __bf16* cw1T = (__bf16*)alloc((size_t)L*16384*2);
  __bf16* cw2T = (__bf16*)alloc((size_t)L*16384*2);
  __bf16* lwT  = (__bf16*)alloc((size_t)L*16384*2);
  __bf16* o1F  = (__bf16*)alloc((size_t)8192*2);
  __bf16* o1T  = (__bf16*)alloc((size_t)8192*2);

  const int egrid = (E+255)/256;
  const int eg64 = (E+63)/64;
  const int eg128 = (E+127)/128;
  const int ngN = (N+63)/64;
  const int wtotal = L*49152;
  const int ntotal = L*16384;

  hipMemsetAsync(d_out, 0, (size_t)out_size*4, stream);
  convw_k<<<(wtotal+255)/256,256,0,stream>>>(mlp_w1, mlp_w2, W1t, W2t, W2c, W1c, wtotal);
  convnw_k<<<(ntotal+255)/256,256,0,stream>>>(conv_w1, conv_w2, lin_w,
    cw1F, cw2F, lwF, cw1T, cw2T, lwT, ntotal);
  convhw_k<<<(8192+255)/256,256,0,stream>>>(out1_w, o1F, o1T);
  edge_geom_k<<<egrid,256,0,stream>>>(pos, ei, offset, cell, wbuf, Cbuf, E);
  embed_k<<<(N*128+255)/256,256,0,stream>>>(emb, z, hbuf, N*128);

  // ---------------- forward ----------------
  for (int i=0;i<L;i++){
    const float* b1i = mlp_b1 + (size_t)i*128;
    const float* b2i = mlp_b2 + (size_t)i*128;
    const float* cb2i= conv_b2+ (size_t)i*128;
    const float* lbi = lin_b  + (size_t)i*128;
    float* xhi = xh   + (size_t)i*N*128;
    float* mi  = mbuf + (size_t)i*N*128;

    ngemm_k<128,8,0,false,0,false><<<ngN,256,0,stream>>>(
      hbuf, nullptr, nullptr, cw1F + (size_t)i*16384, nullptr, nullptr, xhi, N);
    hipMemsetAsync(aggb, 0, (size_t)N*128*4, stream);
    fwd_edge_k<<<eg64,256,0,stream>>>(
      wbuf, Cbuf, ei, E, W1t + (size_t)i*8192, b1i, W2t + (size_t)i*16384, b2i, xhi, aggb);
    ngemm_k<128,8,0,true,0,false><<<ngN,256,0,stream>>>(
      aggb, nullptr, nullptr, cw2F + (size_t)i*16384, cb2i, nullptr, mi, N);
    ngemm_k<128,8,1,true,0,true><<<ngN,256,0,stream>>>(
      mi, nullptr, nullptr, lwF + (size_t)i*16384, lbi, hbuf, hbuf, N);
  }

  // head
  ngemm_k<128,4,0,true,0,false><<<ngN,256,0,stream>>>(
    hbuf, nullptr, nullptr, o1F, out1_b, nullptr, ubuf, N);
  head_k<<<(N+255)/256,256,0,stream>>>(ubuf, out2_w, out2_b, out, N);
  ngemm_k<64,8,3,false,0,false><<<ngN,256,0,stream>>>(
    ubuf, nullptr, out2_w, o1T, nullptr, nullptr, Gbuf, N);

  // ---------------- backward ----------------
  for (int i=L-1;i>=0;i--){
    const float* b1i = mlp_b1 + (size_t)i*128;
    const float* b2i = mlp_b2 + (size_t)i*128;
    float* xhi = xh   + (size_t)i*N*128;
    float* mi  = mbuf + (size_t)i*N*128;
    int first = (i==L-1) ? 0 : 1;

    ngemm_k<128,8,0,false,0,false><<<ngN,256,0,stream>>>(
      Gbuf, nullptr, nullptr, lwT + (size_t)i*16384, nullptr, nullptr, bufA, N);
    ngemm_k<128,8,2,false,0,false><<<ngN,256,0,stream>>>(
      bufA, mi, nullptr, cw2T + (size_t)i*16384, nullptr, nullptr, bufB, N);
    hipMemsetAsync(bufC, 0, (size_t)N*128*4, stream);
    bwd_edge_k<<<eg128,256,0,stream>>>(
      wbuf, Cbuf, ei, E,
      W1t + (size_t)i*8192, b1i, W2t + (size_t)i*16384, b2i,
      W2c + (size_t)i*16384, W1c + (size_t)i*8192,
      bufB, xhi, bufC, dCb, dwb, first);
    ngemm_k<128,8,0,false,0,true><<<ngN,256,0,stream>>>(
      bufC, nullptr, nullptr, cw1T + (size_t)i*16384, nullptr, Gbuf, Gbuf, N);
  }

  force_k<<<egrid,256,0,stream>>>(dwb, dCb, wbuf, pos, ei, offset, cell, out+1, E);
}

// Round 15
// 3811.774 us; speedup vs baseline: 1.0426x; 1.0426x over previous
//
#include <hip/hip_runtime.h>
#include <math.h>

#define LN2F 0.69314718055994530942f
#define PI_F 3.14159265358979323846f
constexpr float DMU = 4.0f/49.0f;          // gaussian spacing, linspace(0,4,50)
constexpr float GC  = -0.5f/(DMU*DMU);     // smearing coeff

typedef __bf16 bf16x8 __attribute__((ext_vector_type(8)));
typedef float  f32x4  __attribute__((ext_vector_type(4)));

// fast-math: v_exp_f32 / v_log_f32 / v_rcp_f32
__device__ __forceinline__ float sspf(float x){
  return fmaxf(x, 0.f) + __logf(1.f + __expf(-fabsf(x))) - LN2F;
}
__device__ __forceinline__ float sigf(float x){
  return __builtin_amdgcn_rcpf(1.f + __expf(-x));
}

// ---------------------------------------------------------------------------
// bf16 MFMA node GEMM: out[M,NT*16] = epi( A'[M,KK] @ B ), fp32 in/out.
// Bt is B^T bf16 [NN][KK], k-contiguous, read from global (L2-resident).
// ATR: 0 none, 1 ssp(A), 2 A*sig(aux[r,k]), 3 auxvec[k]*sig(A)
// OTR: 1 = ssp on output. BIAS adds bias[c]. RES adds res[r,c].
// 64-row tile, 4 waves, wave = 16 rows x NT n-tiles of 16x16x32.
// ---------------------------------------------------------------------------
template<int KK,int NT,int ATR,bool BIAS,int OTR,bool RES>
__global__ __launch_bounds__(256) void ngemm_k(
    const float* __restrict__ A, const float* __restrict__ aux,
    const float* __restrict__ auxvec, const __bf16* __restrict__ Bt,
    const float* __restrict__ bias, const float* __restrict__ res,
    float* __restrict__ out, int M)
{
  constexpr int NN = NT*16;
  constexpr int KP = KK + 8;
  __shared__ __align__(16) __bf16 As[64][KP];
  const int t = threadIdx.x;
  const int m0 = blockIdx.x*64;

  #pragma unroll
  for (int it=0; it<(64*KK)/(8*256); ++it){
    int p = t + it*256;
    int row = p / (KK/8);
    int ko = (p % (KK/8))*8;
    float v[8];
    if (m0+row < M){
      float4 v0 = *(const float4*)(A + (size_t)(m0+row)*KK + ko);
      float4 v1 = *(const float4*)(A + (size_t)(m0+row)*KK + ko + 4);
      v[0]=v0.x; v[1]=v0.y; v[2]=v0.z; v[3]=v0.w;
      v[4]=v1.x; v[5]=v1.y; v[6]=v1.z; v[7]=v1.w;
      if constexpr (ATR==1){
        #pragma unroll
        for (int j=0;j<8;j++) v[j] = sspf(v[j]);
      } else if constexpr (ATR==2){
        float4 a0 = *(const float4*)(aux + (size_t)(m0+row)*KK + ko);
        float4 a1 = *(const float4*)(aux + (size_t)(m0+row)*KK + ko + 4);
        v[0]*=sigf(a0.x); v[1]*=sigf(a0.y); v[2]*=sigf(a0.z); v[3]*=sigf(a0.w);
        v[4]*=sigf(a1.x); v[5]*=sigf(a1.y); v[6]*=sigf(a1.z); v[7]*=sigf(a1.w);
      } else if constexpr (ATR==3){
        #pragma unroll
        for (int j=0;j<8;j++) v[j] = auxvec[ko+j]*sigf(v[j]);
      }
    } else {
      #pragma unroll
      for (int j=0;j<8;j++) v[j] = 0.f;
    }
    bf16x8 o;
    #pragma unroll
    for (int j=0;j<8;j++) o[j] = (__bf16)v[j];
    *(bf16x8*)&As[row][ko] = o;
  }
  __syncthreads();

  const int wid = t>>6, lane = t&63, quad = lane>>4, ln = lane&15;
  f32x4 acc[NT];
  #pragma unroll
  for (int nt=0;nt<NT;nt++) acc[nt] = (f32x4){0.f,0.f,0.f,0.f};

  #pragma unroll
  for (int ks=0; ks<KK; ks+=32){
    bf16x8 a = *(const bf16x8*)&As[wid*16 + ln][ks + quad*8];
    #pragma unroll
    for (int nt=0; nt<NT; nt++){
      bf16x8 b = *(const bf16x8*)(Bt + (size_t)(nt*16+ln)*KK + ks + quad*8);
      acc[nt] = __builtin_amdgcn_mfma_f32_16x16x32_bf16(a, b, acc[nt], 0, 0, 0);
    }
  }

  #pragma unroll
  for (int reg=0; reg<4; reg++){
    int r = m0 + wid*16 + quad*4 + reg;
    if (r < M){
      #pragma unroll
      for (int nt=0; nt<NT; nt++){
        int c = nt*16 + ln;
        float v = acc[nt][reg];
        if constexpr (BIAS) v += bias[c];
        if constexpr (OTR==1) v = sspf(v);
        if constexpr (RES) v += res[(size_t)r*NN + c];
        out[(size_t)r*NN + c] = v;
      }
    }
  }
}

// ---------------------------------------------------------------------------
// Fused FORWARD edge kernel (W2 from global, 18KB LDS, natural occupancy):
//   ea(w) -> s1=ssp(ea@W1+b1) -> Wf=s1@W2+b2 -> agg[col] += xh[row]*Wf*C
// ---------------------------------------------------------------------------
__global__ __launch_bounds__(256) void fwd_edge_k(
    const float* __restrict__ wv, const float* __restrict__ Cv,
    const int* __restrict__ ei, int E,
    const __bf16* __restrict__ W1t, const float* __restrict__ b1,
    const __bf16* __restrict__ W2t, const float* __restrict__ b2,
    const float* __restrict__ xh, float* __restrict__ agg)
{
  __shared__ __align__(16) __bf16 s1t[64][136];    // 17.4 KB
  __shared__ float wrow[64], Ce[64];
  __shared__ int rowi[64], coli[64];
  const int t = threadIdx.x;
  const int e0 = blockIdx.x*64;

  if (t < 64){
    int e = e0 + t;
    bool ok = e < E;
    wrow[t] = ok ? wv[e] : 0.f;
    Ce[t]   = ok ? Cv[e] : 0.f;
    rowi[t] = ok ? ei[e] : 0;
    coli[t] = ok ? ei[E+e] : 0;
  }
  __syncthreads();

  const int wid = t>>6, lane = t&63, quad = lane>>4, ln = lane&15;
  f32x4 acc[8];
  #pragma unroll
  for (int nt=0;nt<8;nt++) acc[nt] = (f32x4){0.f,0.f,0.f,0.f};

  // ---- GEMM1: t1 = ea @ W1 ----
  const float wa = wrow[wid*16 + ln];
  #pragma unroll
  for (int ks=0; ks<64; ks+=32){
    bf16x8 a;
    #pragma unroll
    for (int j=0;j<8;j++){
      int k = ks + quad*8 + j;
      float d = wa - (float)k*DMU;
      a[j] = (k<50) ? (__bf16)__expf(GC*d*d) : (__bf16)0.f;
    }
    #pragma unroll
    for (int nt=0; nt<8; nt++){
      bf16x8 b = *(const bf16x8*)(W1t + (size_t)(nt*16+ln)*64 + ks + quad*8);
      acc[nt] = __builtin_amdgcn_mfma_f32_16x16x32_bf16(a, b, acc[nt], 0, 0, 0);
    }
  }
  #pragma unroll
  for (int nt=0; nt<8; nt++){
    int c = nt*16 + ln;
    float bb = b1[c];
    #pragma unroll
    for (int reg=0; reg<4; reg++){
      int r = wid*16 + quad*4 + reg;
      s1t[r][c] = (__bf16)sspf(acc[nt][reg] + bb);
    }
  }
  __syncthreads();

  // ---- GEMM2: Wf = s1 @ W2 (B from global) ----
  #pragma unroll
  for (int nt=0;nt<8;nt++) acc[nt] = (f32x4){0.f,0.f,0.f,0.f};
  #pragma unroll
  for (int ks=0; ks<128; ks+=32){
    bf16x8 a = *(const bf16x8*)&s1t[wid*16 + ln][ks + quad*8];
    #pragma unroll
    for (int nt=0; nt<8; nt++){
      bf16x8 b = *(const bf16x8*)(W2t + (size_t)(nt*16+ln)*128 + ks + quad*8);
      acc[nt] = __builtin_amdgcn_mfma_f32_16x16x32_bf16(a, b, acc[nt], 0, 0, 0);
    }
  }

  // ---- scatter: agg[col] += xh[row]*(Wf+b2)*C ----
  #pragma unroll
  for (int reg=0; reg<4; reg++){
    int r = wid*16 + quad*4 + reg;
    int e = e0 + r;
    if (e < E){
      float ce = Ce[r];
      size_t ri = (size_t)rowi[r]*128;
      size_t ci = (size_t)coli[r]*128;
      #pragma unroll
      for (int nt=0; nt<8; nt++){
        int c = nt*16 + ln;
        float wf = acc[nt][reg] + b2[c];
        atomicAdd(&agg[ci + c], xh[ri + c]*ce*wf);
      }
    }
  }
}

// ---------------------------------------------------------------------------
// Fused BACKWARD edge kernel (weights from global, 18KB LDS, 4 blocks/CU)
// ---------------------------------------------------------------------------
__global__ __launch_bounds__(256,4) void bwd_edge_k(
    const float* __restrict__ wv, const float* __restrict__ Cv,
    const int* __restrict__ ei, int E,
    const __bf16* __restrict__ W1t, const float* __restrict__ b1,
    const __bf16* __restrict__ W2t, const float* __restrict__ b2,
    const __bf16* __restrict__ W2c, const __bf16* __restrict__ W1c,
    const float* __restrict__ dagg, const float* __restrict__ xh,
    float* __restrict__ dxh, float* __restrict__ dC, float* __restrict__ dw,
    int accum)
{
  __shared__ __align__(16) __bf16 tb[64][136];     // 17.4 KB
  __shared__ float wrow[64], Ce[64];
  __shared__ int rowi[64], coli[64];
  const int t = threadIdx.x;
  const int e0 = blockIdx.x*64;

  if (t < 64){
    int e = e0 + t;
    bool ok = e < E;
    wrow[t] = ok ? wv[e] : 0.f;
    Ce[t]   = ok ? Cv[e] : 0.f;
    rowi[t] = ok ? ei[e] : 0;
    coli[t] = ok ? ei[E+e] : 0;
  }
  __syncthreads();

  const int wid = t>>6, lane = t&63, quad = lane>>4, ln = lane&15;
  f32x4 acc[8];
  float sig[8][4];
  #pragma unroll
  for (int nt=0;nt<8;nt++) acc[nt] = (f32x4){0.f,0.f,0.f,0.f};

  // ---- GEMM1: t1 = ea @ W1 ; keep sig(t1), store ssp(t1) ----
  const float wa = wrow[wid*16 + ln];
  #pragma unroll
  for (int ks=0; ks<64; ks+=32){
    bf16x8 a;
    #pragma unroll
    for (int j=0;j<8;j++){
      int k = ks + quad*8 + j;
      float d = wa - (float)k*DMU;
      a[j] = (k<50) ? (__bf16)__expf(GC*d*d) : (__bf16)0.f;
    }
    #pragma unroll
    for (int nt=0; nt<8; nt++){
      bf16x8 b = *(const bf16x8*)(W1t + (size_t)(nt*16+ln)*64 + ks + quad*8);
      acc[nt] = __builtin_amdgcn_mfma_f32_16x16x32_bf16(a, b, acc[nt], 0, 0, 0);
    }
  }
  #pragma unroll
  for (int nt=0; nt<8; nt++){
    int c = nt*16 + ln;
    float bb = b1[c];
    #pragma unroll
    for (int reg=0; reg<4; reg++){
      int r = wid*16 + quad*4 + reg;
      float t1 = acc[nt][reg] + bb;
      sig[nt][reg] = sigf(t1);
      tb[r][c] = (__bf16)sspf(t1);
    }
  }
  __syncthreads();

  // ---- GEMM2: Wf = s1 @ W2 (B from global) ----
  #pragma unroll
  for (int nt=0;nt<8;nt++) acc[nt] = (f32x4){0.f,0.f,0.f,0.f};
  #pragma unroll
  for (int ks=0; ks<128; ks+=32){
    bf16x8 a = *(const bf16x8*)&tb[wid*16 + ln][ks + quad*8];
    #pragma unroll
    for (int nt=0; nt<8; nt++){
      bf16x8 b = *(const bf16x8*)(W2t + (size_t)(nt*16+ln)*128 + ks + quad*8);
      acc[nt] = __builtin_amdgcn_mfma_f32_16x16x32_bf16(a, b, acc[nt], 0, 0, 0);
    }
  }
  __syncthreads();   // reads of tb (s1) done

  // ---- edge step: dC, dxh scatter, dWf -> tb ----
  #pragma unroll
  for (int reg=0; reg<4; reg++){
    int r = wid*16 + quad*4 + reg;
    int e = e0 + r;
    float dcp = 0.f;
    if (e < E){
      float ce = Ce[r];
      size_t ri = (size_t)rowi[r]*128;
      size_t ci = (size_t)coli[r]*128;
      #pragma unroll
      for (int nt=0; nt<8; nt++){
        int c = nt*16 + ln;
        float wf = acc[nt][reg] + b2[c];
        float da = dagg[ci + c];
        float xv = xh[ri + c];
        dcp += da*xv*wf;
        atomicAdd(&dxh[ri + c], da*ce*wf);
        tb[r][c] = (__bf16)(da*xv*ce);
      }
    } else {
      #pragma unroll
      for (int nt=0; nt<8; nt++) tb[r][nt*16+ln] = (__bf16)0.f;
    }
    dcp += __shfl_xor(dcp, 1);
    dcp += __shfl_xor(dcp, 2);
    dcp += __shfl_xor(dcp, 4);
    dcp += __shfl_xor(dcp, 8);
    if (ln==0 && e < E) dC[e] = accum ? (dC[e]+dcp) : dcp;
  }
  __syncthreads();

  // ---- GEMM3: dt1 = (dWf @ W2^T) * sig (B from global W2c) ----
  #pragma unroll
  for (int nt=0;nt<8;nt++) acc[nt] = (f32x4){0.f,0.f,0.f,0.f};
  #pragma unroll
  for (int ks=0; ks<128; ks+=32){
    bf16x8 a = *(const bf16x8*)&tb[wid*16 + ln][ks + quad*8];
    #pragma unroll
    for (int nt=0; nt<8; nt++){
      bf16x8 b = *(const bf16x8*)(W2c + (size_t)(nt*16+ln)*128 + ks + quad*8);
      acc[nt] = __builtin_amdgcn_mfma_f32_16x16x32_bf16(a, b, acc[nt], 0, 0, 0);
    }
  }
  __syncthreads();   // reads of tb (dWf) done
  #pragma unroll
  for (int nt=0; nt<8; nt++){
    int c = nt*16 + ln;
    #pragma unroll
    for (int reg=0; reg<4; reg++){
      int r = wid*16 + quad*4 + reg;
      tb[r][c] = (__bf16)(acc[nt][reg] * sig[nt][reg]);
    }
  }
  __syncthreads();

  // ---- GEMM4: dea = dt1 @ W1^T ; contract to dw ----
  #pragma unroll
  for (int nt=0;nt<4;nt++) acc[nt] = (f32x4){0.f,0.f,0.f,0.f};
  #pragma unroll
  for (int ks=0; ks<128; ks+=32){
    bf16x8 a = *(const bf16x8*)&tb[wid*16 + ln][ks + quad*8];
    #pragma unroll
    for (int nt=0; nt<4; nt++){
      bf16x8 b = *(const bf16x8*)(W1c + (size_t)(nt*16+ln)*128 + ks + quad*8);
      acc[nt] = __builtin_amdgcn_mfma_f32_16x16x32_bf16(a, b, acc[nt], 0, 0, 0);
    }
  }
  #pragma unroll
  for (int reg=0; reg<4; reg++){
    int r = wid*16 + quad*4 + reg;
    int e = e0 + r;
    float w = wrow[r];
    float s = 0.f;
    #pragma unroll
    for (int nt=0; nt<4; nt++){
      int c = nt*16 + ln;
      if (c < 50){
        float d = w - (float)c*DMU;
        s += acc[nt][reg] * (2.f*GC*d) * __expf(GC*d*d);
      }
    }
    s += __shfl_xor(s, 1);
    s += __shfl_xor(s, 2);
    s += __shfl_xor(s, 4);
    s += __shfl_xor(s, 8);
    if (ln==0 && e < E) dw[e] = accum ? (dw[e]+s) : s;
  }
}

// ---------------------------------------------------------------------------
// one-time bf16 weight conversions
// ---------------------------------------------------------------------------
__global__ void convw_k(const float* __restrict__ w1, const float* __restrict__ w2,
                        __bf16* __restrict__ W1t, __bf16* __restrict__ W2t,
                        __bf16* __restrict__ W2c, __bf16* __restrict__ W1c, int total)
{
  int idx = blockIdx.x*256 + threadIdx.x;
  if (idx >= total) return;
  int l = idx / 49152;
  int r = idx % 49152;
  if (r < 8192){                       // W1t[n][k] = w1[k][n], k<50
    int n = r / 64, k = r % 64;
    float v = (k<50) ? w1[(size_t)l*6400 + k*128 + n] : 0.f;
    W1t[(size_t)l*8192 + r] = (__bf16)v;
  } else if (r < 24576){               // W2t[n][k] = w2[k][n]
    int r2 = r - 8192;
    int n = r2 / 128, k = r2 % 128;
    W2t[(size_t)l*16384 + r2] = (__bf16)w2[(size_t)l*16384 + k*128 + n];
  } else if (r < 40960){               // W2c = w2 (elementwise)
    int r2 = r - 24576;
    W2c[(size_t)l*16384 + r2] = (__bf16)w2[(size_t)l*16384 + r2];
  } else {                             // W1c[n][k] = w1[n][k], n<50
    int r2 = r - 40960;
    int n = r2 / 128, k = r2 % 128;
    float v = (n<50) ? w1[(size_t)l*6400 + n*128 + k] : 0.f;
    W1c[(size_t)l*8192 + r2] = (__bf16)v;
  }
}

// node-weight bf16 layouts: F = B^T of non-transposed use, T = row-major cast
__global__ void convnw_k(const float* __restrict__ cw1, const float* __restrict__ cw2,
                         const float* __restrict__ lw,
                         __bf16* __restrict__ cw1F, __bf16* __restrict__ cw2F,
                         __bf16* __restrict__ lwF,
                         __bf16* __restrict__ cw1T, __bf16* __restrict__ cw2T,
                         __bf16* __restrict__ lwT, int total)
{
  int idx = blockIdx.x*256 + threadIdx.x;
  if (idx >= total) return;
  int l = idx / 16384;
  int r = idx % 16384;
  int a = r / 128, b = r % 128;
  size_t off = (size_t)l*16384;
  cw1F[off+r] = (__bf16)cw1[off + (size_t)b*128 + a];
  cw2F[off+r] = (__bf16)cw2[off + (size_t)b*128 + a];
  lwF [off+r] = (__bf16)lw [off + (size_t)b*128 + a];
  cw1T[off+r] = (__bf16)cw1[off + r];
  cw2T[off+r] = (__bf16)cw2[off + r];
  lwT [off+r] = (__bf16)lw [off + r];
}
__global__ void convhw_k(const float* __restrict__ o1,
                         __bf16* __restrict__ o1F, __bf16* __restrict__ o1T)
{
  int idx = blockIdx.x*256 + threadIdx.x;
  if (idx < 8192){
    int n = idx / 128, k = idx % 128;
    o1F[idx] = (__bf16)o1[(size_t)k*64 + n];
    o1T[idx] = (__bf16)o1[idx];
  }
}

// ---------------------------------------------------------------------------
__global__ void edge_geom_k(const float* __restrict__ pos, const int* __restrict__ ei,
                            const float* __restrict__ off, const float* __restrict__ cell,
                            float* __restrict__ wv, float* __restrict__ Cv, int E)
{
  int e = blockIdx.x*256 + threadIdx.x;
  if (e>=E) return;
  int r = ei[e], c = ei[E+e];
  float o0=off[3*e], o1=off[3*e+1], o2=off[3*e+2];
  float d0 = o0*cell[0] + o1*cell[3] + o2*cell[6];
  float d1 = o0*cell[1] + o1*cell[4] + o2*cell[7];
  float d2 = o0*cell[2] + o1*cell[5] + o2*cell[8];
  float v0 = pos[3*r+0]-pos[3*c+0]+d0;
  float v1 = pos[3*r+1]-pos[3*c+1]+d1;
  float v2 = pos[3*r+2]-pos[3*c+2]+d2;
  float w = sqrtf(v0*v0+v1*v1+v2*v2);
  wv[e]=w;
  Cv[e]=0.5f*cosf(w*(PI_F/4.0f)) + 0.5f;
}

__global__ void embed_k(const float* __restrict__ emb, const int* __restrict__ z,
                        float* __restrict__ h, int total){
  int i = blockIdx.x*256 + threadIdx.x;
  if (i < total){ int n=i>>7, j=i&127; h[i] = emb[(size_t)z[n]*128 + j]; }
}

// readout energy
__global__ void head_k(const float* __restrict__ u, const float* __restrict__ o2,
                       const float* __restrict__ o2b, float* __restrict__ out0, int N){
  int n = blockIdx.x*256 + threadIdx.x;
  float s = 0.f;
  if (n < N){
    #pragma unroll
    for (int k=0;k<64;k+=4){
      float4 uv = *(const float4*)(u + (size_t)n*64 + k);
      float4 ov = *(const float4*)(o2 + k);
      s += sspf(uv.x)*ov.x + sspf(uv.y)*ov.y + sspf(uv.z)*ov.z + sspf(uv.w)*ov.w;
    }
  }
  #pragma unroll
  for (int m=1;m<64;m<<=1) s += __shfl_xor(s, m);
  __shared__ float red[4];
  int lane = threadIdx.x&63, w = threadIdx.x>>6;
  if (lane==0) red[w]=s;
  __syncthreads();
  if (threadIdx.x==0){
    float tot = red[0]+red[1]+red[2]+red[3];
    if (blockIdx.x==0) tot += (float)N * o2b[0];
    atomicAdd(out0, tot);
  }
}

// forces: recompute vec, dvec = vec*(dw + dC*dCdw)/w, atomic scatter to f
__global__ void force_k(const float* __restrict__ dw, const float* __restrict__ dC,
                        const float* __restrict__ wv,
                        const float* __restrict__ pos, const int* __restrict__ ei,
                        const float* __restrict__ off, const float* __restrict__ cell,
                        float* __restrict__ f, int E)
{
  int e = blockIdx.x*256 + threadIdx.x;
  if (e>=E) return;
  int r = ei[e], c = ei[E+e];
  float o0=off[3*e], o1=off[3*e+1], o2=off[3*e+2];
  float d0 = o0*cell[0] + o1*cell[3] + o2*cell[6];
  float d1 = o0*cell[1] + o1*cell[4] + o2*cell[7];
  float d2 = o0*cell[2] + o1*cell[5] + o2*cell[8];
  float v0 = pos[3*r+0]-pos[3*c+0]+d0;
  float v1 = pos[3*r+1]-pos[3*c+1]+d1;
  float v2 = pos[3*r+2]-pos[3*c+2]+d2;
  float w = wv[e];
  float dwt = dw[e] + dC[e] * (-0.5f*(PI_F/4.0f)) * __sinf(w*(PI_F/4.0f));
  float s = dwt / w;
  atomicAdd(&f[3*r+0], -v0*s); atomicAdd(&f[3*r+1], -v1*s); atomicAdd(&f[3*r+2], -v2*s);
  atomicAdd(&f[3*c+0],  v0*s); atomicAdd(&f[3*c+1],  v1*s); atomicAdd(&f[3*c+2],  v2*s);
}

// ---------------------------------------------------------------------------
extern "C" void kernel_launch(void* const* d_in, const int* in_sizes, int n_in,
                              void* d_out, int out_size, void* d_ws, size_t ws_size,
                              hipStream_t stream)
{
  const int N = in_sizes[0];
  const int E = in_sizes[2]/2;
  const int L = 6;
  const int* z        = (const int*)d_in[0];
  const float* pos    = (const float*)d_in[1];
  const int* ei       = (const int*)d_in[2];
  const float* offset = (const float*)d_in[3];
  const float* cell   = (const float*)d_in[4];
  const float* emb    = (const float*)d_in[5];
  const float* mlp_w1 = (const float*)d_in[6];
  const float* mlp_b1 = (const float*)d_in[7];
  const float* mlp_w2 = (const float*)d_in[8];
  const float* mlp_b2 = (const float*)d_in[9];
  const float* conv_w1= (const float*)d_in[10];
  const float* conv_w2= (const float*)d_in[11];
  const float* conv_b2= (const float*)d_in[12];
  const float* lin_w  = (const float*)d_in[13];
  const float* lin_b  = (const float*)d_in[14];
  const float* out1_w = (const float*)d_in[15];
  const float* out1_b = (const float*)d_in[16];
  const float* out2_w = (const float*)d_in[17];
  const float* out2_b = (const float*)d_in[18];
  float* out = (float*)d_out;

  char* wp = (char*)d_ws;
  auto alloc = [&](size_t bytes)->char*{ char* p = wp; wp += (bytes + 255) & ~(size_t)255; return p; };
  float* wbuf = (float*)alloc((size_t)E*4);
  float* Cbuf = (float*)alloc((size_t)E*4);
  float* dCb  = (float*)alloc((size_t)E*4);
  float* dwb  = (float*)alloc((size_t)E*4);
  float* xh   = (float*)alloc((size_t)L*N*128*4);
  float* mbuf = (float*)alloc((size_t)L*N*128*4);
  float* ubuf = (float*)alloc((size_t)N*64*4);
  float* hbuf = (float*)alloc((size_t)N*128*4);
  float* Gbuf = (float*)alloc((size_t)N*128*4);
  float* bufA = (float*)alloc((size_t)N*128*4);
  float* bufB = (float*)alloc((size_t)N*128*4);
  float* bufC = (float*)alloc((size_t)N*128*4);   // dxh
  float* aggb = (float*)alloc((size_t)N*128*4);
  __bf16* W1t = (__bf16*)alloc((size_t)L*8192*2);
  __bf16* W2t = (__bf16*)alloc((size_t)L*16384*2);
  __bf16* W2c = (__bf16*)alloc((size_t)L*16384*2);
  __bf16* W1c = (__bf16*)alloc((size_t)L*8192*2);
  __bf16* cw1F = (__bf16*)alloc((size_t)L*16384*2);
  __bf16* cw2F = (__bf16*)alloc((size_t)L*16384*2);
  __bf16* lwF  = (__bf16*)alloc((size_t)L*16384*2);
  __bf16* cw1T = (__bf16*)alloc((size_t)L*16384*2);
  __bf16* cw2T = (__bf16*)alloc((size_t)L*16384*2);
  __bf16* lwT  = (__bf16*)alloc((size_t)L*16384*2);
  __bf16* o1F  = (__bf16*)alloc((size_t)8192*2);
  __bf16* o1T  = (__bf16*)alloc((size_t)8192*2);

  const int egrid = (E+255)/256;
  const int eg64 = (E+63)/64;
  const int ngN = (N+63)/64;
  const int wtotal = L*49152;
  const int ntotal = L*16384;

  hipMemsetAsync(d_out, 0, (size_t)out_size*4, stream);
  convw_k<<<(wtotal+255)/256,256,0,stream>>>(mlp_w1, mlp_w2, W1t, W2t, W2c, W1c, wtotal);
  convnw_k<<<(ntotal+255)/256,256,0,stream>>>(conv_w1, conv_w2, lin_w,
    cw1F, cw2F, lwF, cw1T, cw2T, lwT, ntotal);
  convhw_k<<<(8192+255)/256,256,0,stream>>>(out1_w, o1F, o1T);
  edge_geom_k<<<egrid,256,0,stream>>>(pos, ei, offset, cell, wbuf, Cbuf, E);
  embed_k<<<(N*128+255)/256,256,0,stream>>>(emb, z, hbuf, N*128);

  // ---------------- forward ----------------
  for (int i=0;i<L;i++){
    const float* b1i = mlp_b1 + (size_t)i*128;
    const float* b2i = mlp_b2 + (size_t)i*128;
    const float* cb2i= conv_b2+ (size_t)i*128;
    const float* lbi = lin_b  + (size_t)i*128;
    float* xhi = xh   + (size_t)i*N*128;
    float* mi  = mbuf + (size_t)i*N*128;

    ngemm_k<128,8,0,false,0,false><<<ngN,256,0,stream>>>(
      hbuf, nullptr, nullptr, cw1F + (size_t)i*16384, nullptr, nullptr, xhi, N);
    hipMemsetAsync(aggb, 0, (size_t)N*128*4, stream);
    fwd_edge_k<<<eg64,256,0,stream>>>(
      wbuf, Cbuf, ei, E, W1t + (size_t)i*8192, b1i, W2t + (size_t)i*16384, b2i, xhi, aggb);
    ngemm_k<128,8,0,true,0,false><<<ngN,256,0,stream>>>(
      aggb, nullptr, nullptr, cw2F + (size_t)i*16384, cb2i, nullptr, mi, N);
    ngemm_k<128,8,1,true,0,true><<<ngN,256,0,stream>>>(
      mi, nullptr, nullptr, lwF + (size_t)i*16384, lbi, hbuf, hbuf, N);
  }

  // head
  ngemm_k<128,4,0,true,0,false><<<ngN,256,0,stream>>>(
    hbuf, nullptr, nullptr, o1F, out1_b, nullptr, ubuf, N);
  head_k<<<(N+255)/256,256,0,stream>>>(ubuf, out2_w, out2_b, out, N);
  ngemm_k<64,8,3,false,0,false><<<ngN,256,0,stream>>>(
    ubuf, nullptr, out2_w, o1T, nullptr, nullptr, Gbuf, N);

  // ---------------- backward ----------------
  for (int i=L-1;i>=0;i--){
    const float* b1i = mlp_b1 + (size_t)i*128;
    const float* b2i = mlp_b2 + (size_t)i*128;
    float* xhi = xh   + (size_t)i*N*128;
    float* mi  = mbuf + (size_t)i*N*128;
    int first = (i==L-1) ? 0 : 1;

    ngemm_k<128,8,0,false,0,false><<<ngN,256,0,stream>>>(
      Gbuf, nullptr, nullptr, lwT + (size_t)i*16384, nullptr, nullptr, bufA, N);
    ngemm_k<128,8,2,false,0,false><<<ngN,256,0,stream>>>(
      bufA, mi, nullptr, cw2T + (size_t)i*16384, nullptr, nullptr, bufB, N);
    hipMemsetAsync(bufC, 0, (size_t)N*128*4, stream);
    bwd_edge_k<<<eg64,256,0,stream>>>(
      wbuf, Cbuf, ei, E,
      W1t + (size_t)i*8192, b1i, W2t + (size_t)i*16384, b2i,
      W2c + (size_t)i*16384, W1c + (size_t)i*8192,
      bufB, xhi, bufC, dCb, dwb, first);
    ngemm_k<128,8,0,false,0,true><<<ngN,256,0,stream>>>(
      bufC, nullptr, nullptr, cw1T + (size_t)i*16384, nullptr, Gbuf, Gbuf, N);
  }

  force_k<<<egrid,256,0,stream>>>(dwb, dCb, wbuf, pos, ei, offset, cell, out+1, E);
}